// Round 4
// baseline (267.652 us; speedup 1.0000x reference)
//
#include <hip/hip_runtime.h>

typedef unsigned short u16;
typedef __attribute__((ext_vector_type(8))) short short8;
typedef __attribute__((ext_vector_type(4))) float f32x4;

#define D_TOT 2048
#define M_TOT 64
#define H_TOT 128
#define B_TOT 256
#define NG    256      /* number of d-slices (each 8 d's) */
#define XB    131072   /* D_TOT*M_TOT : x row stride per b */
#define W1M   262144   /* H_TOT*D_TOT : w1 stride per m */

__device__ __forceinline__ u16 f2bf(float f) {
  unsigned u = __builtin_bit_cast(unsigned, f);
  u = (u + 0x7fffu + ((u >> 16) & 1u)) >> 16;   // round-to-nearest-even
  return (u16)u;
}
__device__ __forceinline__ float bf2f(u16 v) {
  unsigned u = ((unsigned)v) << 16;
  return __builtin_bit_cast(float, u);
}
__device__ __forceinline__ short8 pack8(float4 a, float4 b) {
  short8 t;
  t[0] = (short)f2bf(a.x); t[1] = (short)f2bf(a.y);
  t[2] = (short)f2bf(a.z); t[3] = (short)f2bf(a.w);
  t[4] = (short)f2bf(b.x); t[5] = (short)f2bf(b.y);
  t[6] = (short)f2bf(b.z); t[7] = (short)f2bf(b.w);
  return t;
}

// ---------------------------------------------------------------------------
// phase 0: c[h] = b2[h] + sum_d b1[h,d]*w2[h,d]      grid 128 x 256
// ---------------------------------------------------------------------------
__global__ __launch_bounds__(256)
void nlm_p0(const float* __restrict__ b1, const float* __restrict__ w2,
            const float* __restrict__ b2, float* __restrict__ ch) {
  const int h = blockIdx.x, t = threadIdx.x;
  const float4* pb = (const float4*)(b1 + (size_t)h * D_TOT);
  const float4* pw = (const float4*)(w2 + (size_t)h * D_TOT);
  float s = 0.f;
  for (int i = t; i < D_TOT / 4; i += 256) {
    float4 a = pb[i], w = pw[i];
    s += a.x * w.x + a.y * w.y + a.z * w.z + a.w * w.w;
  }
  __shared__ float red[256];
  red[t] = s;
  __syncthreads();
  for (int off = 128; off > 0; off >>= 1) {
    if (t < off) red[t] += red[t + off];
    __syncthreads();
  }
  if (t == 0) ch[h] = red[0] + b2[h];
}

// ---------------------------------------------------------------------------
// fused main v2: per-block g (8 d's). B' packed directly into LDS (128 KB,
// no Bp round-trip), ONE barrier, then a BARRIER-FREE main loop:
// each wave owns a disjoint 32-row b-range (8 waves x 32 = 256 b) and all
// 128 h. A-fragments are lane-native 32-B contiguous global loads from x
// (per (c,i) the wave covers 16 full 256-B x rows -> coalesced, no dup,
// x traffic exactly once). No As LDS, no inner s_barrier -> waves run
// independently; the unrolled c-loop software-pipelines freely and keeps
// ~8 KB/wave of x loads in flight (64 KB/CU >> BW*latency ~9 KB).
// g-swizzle: XCD k hosts g in [32k,32k+32) -> the 4 g's sharing each 128-B
// w1 line are co-XCD (L2 hits; w1 HBM fetch ~67 MB).
// ---------------------------------------------------------------------------
__global__ __launch_bounds__(512, 2)
void nlm_main(const float* __restrict__ x, const float* __restrict__ w1,
              const float* __restrict__ w2, u16* __restrict__ partial) {
  __shared__ __align__(16) u16 Bs[8 * H_TOT * 64];  // 128 KB, [c][h][m] swizzled

  const int tid  = threadIdx.x;
  const int lane = tid & 63, wave = tid >> 6;
  const int g    = ((blockIdx.x & 7) << 5) + (blockIdx.x >> 3);  // bijective, 256%8==0
  const int d0   = g * 8;
  const int quad = lane >> 4, l16 = lane & 15;

  // per-wave, per-lane x row pointers: row = wb + i*16 + l16, col base quad*8
  const int wb = wave * 32;
  const float* xr0 = x + (size_t)(wb + l16) * XB + (size_t)d0 * M_TOT + quad * 8;
  const float* xr1 = xr0 + (size_t)16 * XB;

  // early-issue c=0 A loads (arrive during pack phase)
  float4 e00a = *(const float4*)(xr0);
  float4 e00b = *(const float4*)(xr0 + 4);
  float4 e01a = *(const float4*)(xr0 + 32);
  float4 e01b = *(const float4*)(xr0 + 36);
  float4 e10a = *(const float4*)(xr1);
  float4 e10b = *(const float4*)(xr1 + 4);
  float4 e11a = *(const float4*)(xr1 + 32);
  float4 e11b = *(const float4*)(xr1 + 36);

  // ---- pack phase: Bs[c][h][m] = bf16(w1[m][h][d0+c] * w2[h][d0+c])
  // task: h = wave*16 + rep (wave-uniform -> w2 scalarizes), m = lane.
  // w1 read = 32-B d-runs; other 96 B of each 128-B line consumed by the
  // 3 co-XCD neighbor blocks via L2.
  {
    const int m = lane;
#pragma unroll 4
    for (int rep = 0; rep < 16; ++rep) {
      const int h = wave * 16 + rep;
      const float* w1p = w1 + (size_t)m * W1M + (size_t)h * D_TOT + d0;
      const float* w2p = w2 + (size_t)h * D_TOT + d0;
      float4 a0 = *(const float4*)(w1p);
      float4 a1 = *(const float4*)(w1p + 4);
      float4 s0 = *(const float4*)(w2p);
      float4 s1 = *(const float4*)(w2p + 4);
      // byte addr = c*16384 + h*128 + ((m*2) ^ ((h&7)<<4))
      u16* dst = (u16*)((char*)Bs + h * 128 + ((m * 2) ^ ((h & 7) << 4)));
      dst[0 * 8192] = f2bf(a0.x * s0.x);
      dst[1 * 8192] = f2bf(a0.y * s0.y);
      dst[2 * 8192] = f2bf(a0.z * s0.z);
      dst[3 * 8192] = f2bf(a0.w * s0.w);
      dst[4 * 8192] = f2bf(a1.x * s1.x);
      dst[5 * 8192] = f2bf(a1.y * s1.y);
      dst[6 * 8192] = f2bf(a1.z * s1.z);
      dst[7 * 8192] = f2bf(a1.w * s1.w);
    }
  }

  // B-fragment byte offsets (j = h/16 block, s = K-slice); +c*16384 per plane.
  // Same XOR involution as the write side (rule #21).
  int boff[8][2];
#pragma unroll
  for (int j = 0; j < 8; ++j) {
    const int hr = j * 16 + l16;
    const int bx = (hr & 7) << 4;
    boff[j][0] = hr * 128 + ((quad * 16) ^ bx);
    boff[j][1] = hr * 128 + ((64 + quad * 16) ^ bx);
  }

  f32x4 acc[2][8];
#pragma unroll
  for (int i = 0; i < 2; ++i)
#pragma unroll
    for (int j = 0; j < 8; ++j) acc[i][j] = (f32x4){0.f, 0.f, 0.f, 0.f};

  __syncthreads();   // the ONLY block-wide barrier

#pragma unroll
  for (int c = 0; c < 8; ++c) {
    short8 a00, a01, a10, a11;   // af[i][s]
    if (c == 0) {
      a00 = pack8(e00a, e00b); a01 = pack8(e01a, e01b);
      a10 = pack8(e10a, e10b); a11 = pack8(e11a, e11b);
    } else {
      const float* p0 = xr0 + c * M_TOT;
      const float* p1 = xr1 + c * M_TOT;
      a00 = pack8(*(const float4*)(p0),      *(const float4*)(p0 + 4));
      a01 = pack8(*(const float4*)(p0 + 32), *(const float4*)(p0 + 36));
      a10 = pack8(*(const float4*)(p1),      *(const float4*)(p1 + 4));
      a11 = pack8(*(const float4*)(p1 + 32), *(const float4*)(p1 + 36));
    }
    const char* Bb = (const char*)Bs + c * 16384;
#pragma unroll
    for (int s = 0; s < 2; ++s) {
      const short8 f0 = s ? a01 : a00;
      const short8 f1 = s ? a11 : a10;
#pragma unroll
      for (int j = 0; j < 8; ++j) {
        short8 bf = *(const short8*)(Bb + boff[j][s]);
        acc[0][j] = __builtin_amdgcn_mfma_f32_16x16x32_bf16(f0, bf, acc[0][j], 0, 0, 0);
        acc[1][j] = __builtin_amdgcn_mfma_f32_16x16x32_bf16(f1, bf, acc[1][j], 0, 0, 0);
      }
    }
  }

  // ---- epilogue: partial[b][g][h], 16 consecutive lanes (l16) write 32-B
  // contiguous u16 runs; quads cover different b rows.
#pragma unroll
  for (int i = 0; i < 2; ++i)
#pragma unroll
    for (int j = 0; j < 8; ++j) {
      const int hcol = j * 16 + l16;
#pragma unroll
      for (int r = 0; r < 4; ++r) {
        const int brow = wb + i * 16 + quad * 4 + r;
        partial[((size_t)brow * NG + g) * H_TOT + hcol] = f2bf(acc[i][j][r]);
      }
    }
}

// ---------------------------------------------------------------------------
// phase 2: out[b,h] = sum_g partial[b][g][h] + c[h]     grid 256 x 256
// ---------------------------------------------------------------------------
__global__ __launch_bounds__(256)
void nlm_p2(const u16* __restrict__ partial, const float* __restrict__ ch,
            float* __restrict__ out) {
  const int b = blockIdx.x, t = threadIdx.x;
  const int h2   = t & 63;    // ushort2 column: h = 2*h2, 2*h2+1
  const int half = t >> 6;    // 0..3 : g range
  const u16* base = partial + ((size_t)b * NG + half * 64) * H_TOT + 2 * h2;
  float s0 = 0.f, s1 = 0.f;
#pragma unroll 8
  for (int gg = 0; gg < 64; ++gg) {
    unsigned v = __builtin_nontemporal_load((const unsigned*)(base + (size_t)gg * H_TOT));
    s0 += bf2f((u16)(v & 0xffffu));
    s1 += bf2f((u16)(v >> 16));
  }
  __shared__ float red0[256], red1[256];
  red0[t] = s0;
  red1[t] = s1;
  __syncthreads();
  if (t < 64) {
    float a0 = red0[t] + red0[t + 64] + red0[t + 128] + red0[t + 192];
    float a1 = red1[t] + red1[t + 64] + red1[t + 128] + red1[t + 192];
    out[(size_t)b * H_TOT + 2 * t]     = a0 + ch[2 * t];
    out[(size_t)b * H_TOT + 2 * t + 1] = a1 + ch[2 * t + 1];
  }
}

// ---------------------------------------------------------------------------
extern "C" void kernel_launch(void* const* d_in, const int* in_sizes, int n_in,
                              void* d_out, int out_size, void* d_ws, size_t ws_size,
                              hipStream_t stream) {
  const float* x  = (const float*)d_in[0];
  const float* w1 = (const float*)d_in[1];
  const float* b1 = (const float*)d_in[2];
  const float* w2 = (const float*)d_in[3];
  const float* b2 = (const float*)d_in[4];
  float* out = (float*)d_out;

  // ws: partial 16.78 MB | ch 512 B
  u16*   partial = (u16*)d_ws;
  float* ch      = (float*)((char*)d_ws + (size_t)B_TOT * NG * H_TOT * sizeof(u16));

  nlm_p0<<<dim3(128),   dim3(256), 0, stream>>>(b1, w2, b2, ch);
  nlm_main<<<dim3(256), dim3(512), 0, stream>>>(x, w1, w2, partial);
  nlm_p2<<<dim3(256),   dim3(256), 0, stream>>>(partial, ch, out);
}

// Round 5
// 261.993 us; speedup vs baseline: 1.0216x; 1.0216x over previous
//
#include <hip/hip_runtime.h>

typedef unsigned short u16;
typedef __attribute__((ext_vector_type(8))) short short8;
typedef __attribute__((ext_vector_type(4))) float f32x4;

#define D_TOT 2048
#define M_TOT 64
#define H_TOT 128
#define B_TOT 256
#define NG    256      /* number of d-slices (each 8 d's) */
#define XB    131072   /* D_TOT*M_TOT : x row stride per b */
#define W1M   262144   /* H_TOT*D_TOT : w1 stride per m */

__device__ __forceinline__ u16 f2bf(float f) {
  unsigned u = __builtin_bit_cast(unsigned, f);
  u = (u + 0x7fffu + ((u >> 16) & 1u)) >> 16;   // round-to-nearest-even
  return (u16)u;
}
__device__ __forceinline__ float bf2f(u16 v) {
  unsigned u = ((unsigned)v) << 16;
  return __builtin_bit_cast(float, u);
}
__device__ __forceinline__ short8 pack8(float4 a, float4 b) {
  short8 t;
  t[0] = (short)f2bf(a.x); t[1] = (short)f2bf(a.y);
  t[2] = (short)f2bf(a.z); t[3] = (short)f2bf(a.w);
  t[4] = (short)f2bf(b.x); t[5] = (short)f2bf(b.y);
  t[6] = (short)f2bf(b.z); t[7] = (short)f2bf(b.w);
  return t;
}

// ---------------------------------------------------------------------------
// pw (+ fused p0): pre-pack B'[g][c][h][m] = bf16( w1[m][h][g*8+c] * w2[h][g*8+c] ).
// Round-1-measured version, verbatim. grid 1024 = 64 gq x 16 hb, 32 KB tile;
// blocks 1024..1151 compute ch[h] = b2[h] + sum_d b1[h,d]*w2[h,d].
// ---------------------------------------------------------------------------
__global__ __launch_bounds__(256)
void nlm_pw(const float* __restrict__ w1, const float* __restrict__ w2,
            const float* __restrict__ b1, const float* __restrict__ b2,
            u16* __restrict__ Bp, float* __restrict__ ch) {
  __shared__ __align__(16) u16 tile[32 * 8 * 64];  // [dc][h_l][m] = 32 KB
  const int t = threadIdx.x;

  if (blockIdx.x >= 1024) {  // ---- p0 path (block-uniform branch)
    const int h = blockIdx.x - 1024;
    const float4* pb = (const float4*)(b1 + (size_t)h * D_TOT);
    const float4* pw = (const float4*)(w2 + (size_t)h * D_TOT);
    float s = 0.f;
    for (int i = t; i < D_TOT / 4; i += 256) {
      float4 a = pb[i], w = pw[i];
      s += a.x * w.x + a.y * w.y + a.z * w.z + a.w * w.w;
    }
    float* red = (float*)tile;
    red[t] = s;
    __syncthreads();
    for (int off = 128; off > 0; off >>= 1) {
      if (t < off) red[t] += red[t + off];
      __syncthreads();
    }
    if (t == 0) ch[h] = red[0] + b2[h];
    return;
  }

  const int gq  = blockIdx.x & 63;   // 32-d quad
  const int hb  = blockIdx.x >> 6;   // 16 h-blocks of 8 h
  const int dq0 = gq * 32;

#pragma unroll
  for (int rep = 0; rep < 2; ++rep) {
    const int tau = rep * 256 + t;
    const int h_l = tau >> 6, m = tau & 63;
    const int h   = hb * 8 + h_l;
    const float* w1p = w1 + (size_t)m * W1M + (size_t)h * D_TOT + dq0;
    const float* w2p = w2 + (size_t)h * D_TOT + dq0;
    u16* dst = tile + h_l * 64 + m;   // + dc*512
#pragma unroll
    for (int q = 0; q < 8; ++q) {      // 8 x float4 = the full 128-B line
      float4 a = *(const float4*)(w1p + q * 4);
      float4 s = *(const float4*)(w2p + q * 4);
      dst[(q * 4 + 0) * 512] = f2bf(a.x * s.x);
      dst[(q * 4 + 1) * 512] = f2bf(a.y * s.y);
      dst[(q * 4 + 2) * 512] = f2bf(a.z * s.z);
      dst[(q * 4 + 3) * 512] = f2bf(a.w * s.w);
    }
  }
  __syncthreads();
  // write out 32 contiguous 1-KB segments (one per dc)
#pragma unroll 4
  for (int dc = 0; dc < 32; ++dc) {
    const int g = gq * 4 + (dc >> 3), c = dc & 7;
    u16* out = Bp + (((size_t)g * 8 + c) * H_TOT + hb * 8) * 64 + t * 2;
    *(ushort2*)out = *(const ushort2*)(tile + dc * 512 + t * 2);
  }
}

// ---------------------------------------------------------------------------
// phase 1 v5: partial[b][g][h] += x * B'.  Round-1 structure (coalesced LDS
// staging: wave reads contiguous 256-B x runs -> DRAM-friendly; pad-72 LDS;
// 16 waves/CU) with two fixes:
//  - 128 b-rows/block (grid 512 = 2 bq x 256 g): 2x work per barrier-pair.
//  - depth-2 register prefetch across RAW s_barriers (lgkmcnt(0) only, vmcnt
//    NEVER drained): loads for c+2 issued between the barriers stay in
//    flight across both; the wait lands at the conversion two iters later.
// block 512 = 8 waves as 4(bm) x 2(hn); per-wave tile 32b x 64h.
// blockIdx%8 = g%8 -> the 2 bq sharing a g are co-XCD (Bp L2 reuse).
// ---------------------------------------------------------------------------
__global__ __launch_bounds__(512, 4)
void nlm_p1(const float* __restrict__ x, const u16* __restrict__ Bp,
            u16* __restrict__ partial) {
  __shared__ __align__(16) u16 As[128 * 72];   // row b_l: 64 m + 8 pad
  __shared__ __align__(16) u16 Bs[128 * 72];   // row h:   64 m + 8 pad

  const int tid  = threadIdx.x;
  const int g    = blockIdx.x & 255;
  const int bq   = blockIdx.x >> 8;
  const int d0   = g * 8;
  const int lane = tid & 63, wave = tid >> 6;
  const int wm   = wave & 3;          // 0..3 (b-subtile of 32)
  const int wn   = wave >> 2;         // 0..1 (h-subtile of 64)
  const int quad = lane >> 4, l16 = lane & 15;

  // A staging: thread -> (b_l = tid>>2, part = tid&3): 64 B of one x row;
  // 4 consecutive lanes cover a full 256-B m-run (DRAM-sequential).
  const int a_bl = tid >> 2, a_p = tid & 3;
  const float* xrow = x + (size_t)(bq * 128 + a_bl) * XB
                        + (size_t)d0 * M_TOT + a_p * 16;
  // B staging: thread -> (h = tid>>2, qp = tid&3): 32 B of B' chunk
  const int b_h = tid >> 2, b_qp = tid & 3;
  const u16* bsrc = Bp + ((size_t)g * 8 * H_TOT + b_h) * 64 + b_qp * 16;

  f32x4 acc[2][4];
#pragma unroll
  for (int i = 0; i < 2; ++i)
#pragma unroll
    for (int j = 0; j < 4; ++j) acc[i][j] = (f32x4){0.f, 0.f, 0.f, 0.f};

  // prefetch slots: slot k holds loads for iteration with (c&1)==k
  float4 A0q0, A0q1, A0q2, A0q3;  short8 B0v0, B0v1;   // slot 0
  float4 A1q0, A1q1, A1q2, A1q3;  short8 B1v0, B1v1;   // slot 1

  { // prologue: issue c=0 -> slot0, c=1 -> slot1
    const float* p = xrow;
    A0q0 = *(const float4*)(p);      A0q1 = *(const float4*)(p + 4);
    A0q2 = *(const float4*)(p + 8);  A0q3 = *(const float4*)(p + 12);
    B0v0 = *(const short8*)(bsrc);   B0v1 = *(const short8*)(bsrc + 8);
    const float* q = xrow + 1 * M_TOT;
    A1q0 = *(const float4*)(q);      A1q1 = *(const float4*)(q + 4);
    A1q2 = *(const float4*)(q + 8);  A1q3 = *(const float4*)(q + 12);
    const u16* bp = bsrc + (size_t)1 * (H_TOT * 64);
    B1v0 = *(const short8*)(bp);     B1v1 = *(const short8*)(bp + 8);
  }

#pragma unroll
  for (int c = 0; c < 8; ++c) {
    { // ---- stage tile c from slot (c&1): the ONLY place vmcnt is waited,
      // for loads issued 2 iterations ago (fully hidden).
      float4 q0 = (c & 1) ? A1q0 : A0q0;
      float4 q1 = (c & 1) ? A1q1 : A0q1;
      float4 q2 = (c & 1) ? A1q2 : A0q2;
      float4 q3 = (c & 1) ? A1q3 : A0q3;
      short8 v0 = (c & 1) ? B1v0 : B0v0;
      short8 v1 = (c & 1) ? B1v1 : B0v1;
      *(short8*)(As + a_bl * 72 + a_p * 16)     = pack8(q0, q1);
      *(short8*)(As + a_bl * 72 + a_p * 16 + 8) = pack8(q2, q3);
      *(short8*)(Bs + b_h * 72 + b_qp * 16)     = v0;
      *(short8*)(Bs + b_h * 72 + b_qp * 16 + 8) = v1;
    }
    // raw barrier: drain LDS writes only; vmcnt stays un-drained.
    asm volatile("s_waitcnt lgkmcnt(0)" ::: "memory");
    __builtin_amdgcn_s_barrier();

    // ---- issue loads for c+2 into slot (c&1) (regs just consumed above)
    if (c + 2 < 8) {
      const float* p = xrow + (c + 2) * M_TOT;
      const u16*  bp = bsrc + (size_t)(c + 2) * (H_TOT * 64);
      if ((c & 1) == 0) {
        A0q0 = *(const float4*)(p);      A0q1 = *(const float4*)(p + 4);
        A0q2 = *(const float4*)(p + 8);  A0q3 = *(const float4*)(p + 12);
        B0v0 = *(const short8*)(bp);     B0v1 = *(const short8*)(bp + 8);
      } else {
        A1q0 = *(const float4*)(p);      A1q1 = *(const float4*)(p + 4);
        A1q2 = *(const float4*)(p + 8);  A1q3 = *(const float4*)(p + 12);
        B1v0 = *(const short8*)(bp);     B1v1 = *(const short8*)(bp + 8);
      }
    }

    // ---- frag reads + MFMA (compiler auto-inserts counted lgkm waits)
#pragma unroll
    for (int s = 0; s < 2; ++s) {
      short8 af[2], bfr[4];
#pragma unroll
      for (int i = 0; i < 2; ++i)
        af[i] = *(const short8*)(As + (wm * 32 + i * 16 + l16) * 72 + s * 32 + quad * 8);
#pragma unroll
      for (int j = 0; j < 4; ++j)
        bfr[j] = *(const short8*)(Bs + (wn * 64 + j * 16 + l16) * 72 + s * 32 + quad * 8);
#pragma unroll
      for (int i = 0; i < 2; ++i)
#pragma unroll
        for (int j = 0; j < 4; ++j)
          acc[i][j] = __builtin_amdgcn_mfma_f32_16x16x32_bf16(af[i], bfr[j], acc[i][j], 0, 0, 0);
    }
    // reads complete (lgkmcnt(0)) before any wave starts next writes.
    asm volatile("s_waitcnt lgkmcnt(0)" ::: "memory");
    __builtin_amdgcn_s_barrier();
  }

  // ---- epilogue: bf16 partials [b][g][h]; wn 0..1 x j 0..3 cover the full
  // 256-B h-row -> L2 write-combines full lines.
#pragma unroll
  for (int i = 0; i < 2; ++i)
#pragma unroll
    for (int j = 0; j < 4; ++j) {
      const int hcol = wn * 64 + j * 16 + l16;
#pragma unroll
      for (int r = 0; r < 4; ++r) {
        const int brow = bq * 128 + wm * 32 + i * 16 + quad * 4 + r;
        partial[((size_t)brow * NG + g) * H_TOT + hcol] = f2bf(acc[i][j][r]);
      }
    }
}

// ---------------------------------------------------------------------------
// phase 2: out[b,h] = sum_g partial[b][g][h] + c[h]     grid 256 x 256
// ---------------------------------------------------------------------------
__global__ __launch_bounds__(256)
void nlm_p2(const u16* __restrict__ partial, const float* __restrict__ ch,
            float* __restrict__ out) {
  const int b = blockIdx.x, t = threadIdx.x;
  const int h2   = t & 63;    // ushort2 column: h = 2*h2, 2*h2+1
  const int half = t >> 6;    // 0..3 : g range
  const u16* base = partial + ((size_t)b * NG + half * 64) * H_TOT + 2 * h2;
  float s0 = 0.f, s1 = 0.f;
#pragma unroll 8
  for (int gg = 0; gg < 64; ++gg) {
    unsigned v = __builtin_nontemporal_load((const unsigned*)(base + (size_t)gg * H_TOT));
    s0 += bf2f((u16)(v & 0xffffu));
    s1 += bf2f((u16)(v >> 16));
  }
  __shared__ float red0[256], red1[256];
  red0[t] = s0;
  red1[t] = s1;
  __syncthreads();
  if (t < 64) {
    float a0 = red0[t] + red0[t + 64] + red0[t + 128] + red0[t + 192];
    float a1 = red1[t] + red1[t + 64] + red1[t + 128] + red1[t + 192];
    out[(size_t)b * H_TOT + 2 * t]     = a0 + ch[2 * t];
    out[(size_t)b * H_TOT + 2 * t + 1] = a1 + ch[2 * t + 1];
  }
}

// ---------------------------------------------------------------------------
extern "C" void kernel_launch(void* const* d_in, const int* in_sizes, int n_in,
                              void* d_out, int out_size, void* d_ws, size_t ws_size,
                              hipStream_t stream) {
  const float* x  = (const float*)d_in[0];
  const float* w1 = (const float*)d_in[1];
  const float* b1 = (const float*)d_in[2];
  const float* w2 = (const float*)d_in[3];
  const float* b2 = (const float*)d_in[4];
  float* out = (float*)d_out;

  // ws: partial 16.78 MB | B' 33.55 MB | ch 512 B   (needs ~50.4 MB)
  u16*   partial = (u16*)d_ws;
  u16*   Bp      = (u16*)((char*)d_ws + (size_t)B_TOT * NG * H_TOT * sizeof(u16));
  float* ch      = (float*)((char*)d_ws + (size_t)B_TOT * NG * H_TOT * sizeof(u16)
                                        + (size_t)NG * 8 * H_TOT * 64 * sizeof(u16));

  nlm_pw<<<dim3(1152), dim3(256), 0, stream>>>(w1, w2, b1, b2, Bp, ch);
  nlm_p1<<<dim3(512),  dim3(512), 0, stream>>>(x, Bp, partial);
  nlm_p2<<<dim3(256),  dim3(256), 0, stream>>>(partial, ch, out);
}